// Round 1
// baseline (11332.497 us; speedup 1.0000x reference)
//
#include <hip/hip_runtime.h>
#include <cstdint>
#include <cstddef>

// SokobanNCA: 2048 independent samples, 50 steps of
//   relu(conv3x3 5->128) -> relu(conv3x3 128->128) -> 4x relu(conv1x1 128->128)
//   -> conv1x1 128->5 -> x += dx -> softmax(x/T, ch)
// One workgroup (256 thr / 4 waves) per sample; all 50 steps fused in-kernel.
// bf16 MFMA (16x16x32) with fp32 accumulation; x state + softmax in fp32.

#define NSAMPLES 2048
#define PM    112      // M padded to 7 tiles of 16 (100 real pixels)
#define HROW  136      // bf16 elems per h row (272 B stride: 16B aligned, bank-safe)
#define A1ROW 72       // bf16 elems per A1 row (144 B stride)
#define ZROW  112      // index of the always-zero row in hA (conv2 zero padding)

typedef __attribute__((ext_vector_type(8))) short bf16x8;
typedef __attribute__((ext_vector_type(4))) float f32x4;

#define MFMA16(A, B, C) __builtin_amdgcn_mfma_f32_16x16x32_bf16((A), (B), (C), 0, 0, 0)

__device__ __forceinline__ short f2bf(float f) {
  unsigned u = __float_as_uint(f);
  return (short)((u + 0x7FFFu + ((u >> 16) & 1u)) >> 16);  // RNE
}

// ---------------- weight pre-pack: fp32 -> bf16 in exact MFMA B-fragment order -------
// Packed layout: [ktile][ntile][lane 0..63][j 0..7], element = B[k][n] with
//   k = ktile*32 + (lane>>4)*8 + j,  n = ntile*16 + (lane&15)
// mode 0: 1x1 conv,  w[n*Kact + k]           (zeros for k>=Kact or n>=Nact)
// mode 1: conv p1 im2col, k = s*5+cin (k<45), w[n*45 + cin*9 + s]
// mode 2: conv p2, ktile = s*4+ksub, kk = ksub*32+..., w[n*1152 + kk*9 + s]
__global__ void prepack_kernel(const float* __restrict__ w, short* __restrict__ dst,
                               int mode, int ntc, int Kact, int Nact, int total) {
  int idx = blockIdx.x * 256 + threadIdx.x;
  if (idx >= total) return;
  int j = idx & 7, l = (idx >> 3) & 63, t = idx >> 9;
  int nt = t % ntc, kt = t / ntc;
  int kg = kt * 32 + (l >> 4) * 8 + j;
  int n  = nt * 16 + (l & 15);
  float v = 0.f;
  if (mode == 0) {
    if (kg < Kact && n < Nact) v = w[n * Kact + kg];
  } else if (mode == 1) {
    if (kg < 45) { int s = kg / 5, cin = kg - 5 * s; v = w[n * 45 + cin * 9 + s]; }
  } else {
    int s = kt >> 2;
    int kk = (kt & 3) * 32 + (l >> 4) * 8 + j;
    v = w[n * 1152 + kk * 9 + s];
  }
  dst[idx] = f2bf(v);
}

// ---------------- helpers ----------------
__device__ __forceinline__ void store_relu_bf16(short* dst, f32x4 (&acc)[7][2],
                                                float b0, float b1,
                                                int w, int lr, int grp) {
#pragma unroll
  for (int m = 0; m < 7; ++m) {
#pragma unroll
    for (int nt = 0; nt < 2; ++nt) {
      int col = (2 * w + nt) * 16 + lr;
      float bb = nt ? b1 : b0;
#pragma unroll
      for (int rg = 0; rg < 4; ++rg) {
        int row = 16 * m + 4 * grp + rg;
        dst[row * HROW + col] = f2bf(fmaxf(acc[m][nt][rg] + bb, 0.f));
      }
    }
  }
}

__device__ __forceinline__ void conv1x1_layer(const short* src, short* dst,
                                              const short* __restrict__ Wp,
                                              float b0, float b1,
                                              int w, int l, int lr, int grp) {
  const f32x4 fz = {0.f, 0.f, 0.f, 0.f};
  f32x4 acc[7][2];
#pragma unroll
  for (int m = 0; m < 7; ++m) { acc[m][0] = fz; acc[m][1] = fz; }
  bf16x8 Bf[4][2];
#pragma unroll
  for (int kt = 0; kt < 4; ++kt) {
    Bf[kt][0] = *(const bf16x8*)&Wp[((kt * 8 + 2 * w    ) * 64 + l) * 8];
    Bf[kt][1] = *(const bf16x8*)&Wp[((kt * 8 + 2 * w + 1) * 64 + l) * 8];
  }
#pragma unroll
  for (int kt = 0; kt < 4; ++kt) {
#pragma unroll
    for (int m = 0; m < 7; ++m) {   // m inner: 14 independent acc chains
      bf16x8 Af = *(const bf16x8*)&src[(16 * m + lr) * HROW + kt * 32 + grp * 8];
      acc[m][0] = MFMA16(Af, Bf[kt][0], acc[m][0]);
      acc[m][1] = MFMA16(Af, Bf[kt][1], acc[m][1]);
    }
  }
  store_relu_bf16(dst, acc, b0, b1, w, lr, grp);
}

// ---------------- main fused NCA kernel ----------------
__global__ __launch_bounds__(256, 2) void nca_kernel(
    const float* __restrict__ x_in,
    const float* __restrict__ bias1p, const float* __restrict__ bias2p,
    const float* __restrict__ bias3p, const float* __restrict__ bias4p,
    const float* __restrict__ bias5p, const float* __restrict__ bias6p,
    const float* __restrict__ bias7p,
    const short* __restrict__ W1, const short* __restrict__ W2,
    const short* __restrict__ W3, const short* __restrict__ W4,
    const short* __restrict__ W5, const short* __restrict__ W6,
    const short* __restrict__ W7,
    const int* __restrict__ steps_ptr,
    float* __restrict__ d_out) {
  // LDS: 79,568 B total -> 2 WGs/CU
  __shared__ __align__(16) short hA[(PM + 1) * HROW];  // +1 zero row for conv2 padding
  __shared__ __align__(16) short hB[PM * HROW];
  __shared__ __align__(16) short A1s[PM * A1ROW];      // im2col for conv1; aliased as dx (f32)
  __shared__ __align__(16) float xs[5 * PM];           // fp32 state [c][p]

  const int sample = blockIdx.x;
  const int tid = threadIdx.x;
  const int l   = tid & 63;
  const int w   = tid >> 6;
  const int lr  = l & 15;
  const int grp = l >> 4;
  const int steps = *steps_ptr;
  const f32x4 fz = {0.f, 0.f, 0.f, 0.f};

  // zero the padding row of hA (never overwritten: stores only touch rows 0..111)
  for (int i = tid; i < HROW; i += 256) hA[ZROW * HROW + i] = 0;
  // load x state
  for (int i = tid; i < 500; i += 256) {
    int c = i / 100, p = i - c * 100;
    xs[c * PM + p] = x_in[(size_t)sample * 500 + i];
  }
  // hoist biases (constant across steps)
  float bv[6][2];
  {
    const float* bp[6] = {bias1p, bias2p, bias3p, bias4p, bias5p, bias6p};
#pragma unroll
    for (int li = 0; li < 6; ++li) {
      bv[li][0] = bp[li][(2 * w) * 16 + lr];
      bv[li][1] = bp[li][(2 * w + 1) * 16 + lr];
    }
  }
  float b7v = (lr < 5) ? bias7p[lr] : 0.f;
  // per-lane pixel geometry per M-tile (for conv2 shift masking)
  int rr_[7], cc_[7], pv_[7];
#pragma unroll
  for (int m = 0; m < 7; ++m) {
    int p = 16 * m + lr;
    int pc = p < 99 ? p : 99;
    rr_[m] = pc / 10;
    cc_[m] = pc - 10 * rr_[m];
    pv_[m] = (p < 100) ? 1 : 0;
  }
  float* dxb = (float*)A1s;  // dx buffer aliases A1 (disjoint lifetimes, barrier-separated)
  __syncthreads();

  for (int step = 0; step < steps; ++step) {
    // ---- build A1 im2col (bf16) from fp32 x: A1[p][s*5+cin], zeros at pad/border ----
    for (int i = tid; i < PM * 64; i += 256) {
      int p = i >> 6, k = i & 63;
      float v = 0.f;
      if (p < 100 && k < 45) {
        int s = k / 5, cin = k - 5 * s;
        int r = p / 10, c = p - 10 * r;
        int r2 = r + s / 3 - 1, c2 = c + s % 3 - 1;
        if ((unsigned)r2 < 10u && (unsigned)c2 < 10u) v = xs[cin * PM + r2 * 10 + c2];
      }
      A1s[p * A1ROW + k] = f2bf(v);
    }
    __syncthreads();

    // ---- conv1 (p1, 3x3 via im2col, K=64): A1 @ W1 -> hA ----
    {
      f32x4 acc[7][2];
#pragma unroll
      for (int m = 0; m < 7; ++m) { acc[m][0] = fz; acc[m][1] = fz; }
#pragma unroll
      for (int kt = 0; kt < 2; ++kt) {
        bf16x8 B0 = *(const bf16x8*)&W1[((kt * 8 + 2 * w    ) * 64 + l) * 8];
        bf16x8 B1 = *(const bf16x8*)&W1[((kt * 8 + 2 * w + 1) * 64 + l) * 8];
#pragma unroll
        for (int m = 0; m < 7; ++m) {
          bf16x8 Af = *(const bf16x8*)&A1s[(16 * m + lr) * A1ROW + kt * 32 + grp * 8];
          acc[m][0] = MFMA16(Af, B0, acc[m][0]);
          acc[m][1] = MFMA16(Af, B1, acc[m][1]);
        }
      }
      store_relu_bf16(hA, acc, bv[0][0], bv[0][1], w, lr, grp);
    }
    __syncthreads();

    // ---- conv2 (p2, 3x3, K=9*128 via shift decomposition): hA -> hB ----
    {
      f32x4 acc[7][2];
#pragma unroll
      for (int m = 0; m < 7; ++m) { acc[m][0] = fz; acc[m][1] = fz; }
      for (int s = 0; s < 9; ++s) {
        int dr = s / 3 - 1, dc = s - 3 * (s / 3) - 1;
        int doff = dr * 10 + dc;
        int prow[7];
#pragma unroll
        for (int m = 0; m < 7; ++m) {
          bool ok = pv_[m] && ((unsigned)(rr_[m] + dr) < 10u) && ((unsigned)(cc_[m] + dc) < 10u);
          prow[m] = ok ? (16 * m + lr + doff) : ZROW;  // ZROW = zero row => zero padding
        }
        bf16x8 Bf[4][2];
#pragma unroll
        for (int kt = 0; kt < 4; ++kt) {
          Bf[kt][0] = *(const bf16x8*)&W2[(((s * 4 + kt) * 8 + 2 * w    ) * 64 + l) * 8];
          Bf[kt][1] = *(const bf16x8*)&W2[(((s * 4 + kt) * 8 + 2 * w + 1) * 64 + l) * 8];
        }
#pragma unroll
        for (int kt = 0; kt < 4; ++kt) {
#pragma unroll
          for (int m = 0; m < 7; ++m) {
            bf16x8 Af = *(const bf16x8*)&hA[prow[m] * HROW + kt * 32 + grp * 8];
            acc[m][0] = MFMA16(Af, Bf[kt][0], acc[m][0]);
            acc[m][1] = MFMA16(Af, Bf[kt][1], acc[m][1]);
          }
        }
      }
      store_relu_bf16(hB, acc, bv[1][0], bv[1][1], w, lr, grp);
    }
    __syncthreads();

    // ---- four 1x1 convs (p3, u1, u2, u3), ping-pong hB<->hA ----
    conv1x1_layer(hB, hA, W3, bv[2][0], bv[2][1], w, l, lr, grp); __syncthreads();
    conv1x1_layer(hA, hB, W4, bv[3][0], bv[3][1], w, l, lr, grp); __syncthreads();
    conv1x1_layer(hB, hA, W5, bv[4][0], bv[4][1], w, l, lr, grp); __syncthreads();
    conv1x1_layer(hA, hB, W6, bv[5][0], bv[5][1], w, l, lr, grp); __syncthreads();

    // ---- conv7 (u4, 1x1 128->5, no relu): hB -> dx (fp32, aliases A1) ----
    {
      f32x4 a7[2] = {fz, fz};
      bf16x8 Bf7[4];
#pragma unroll
      for (int kt = 0; kt < 4; ++kt) Bf7[kt] = *(const bf16x8*)&W7[(kt * 64 + l) * 8];
#pragma unroll
      for (int m2 = 0; m2 < 2; ++m2) {
        int m = w + 4 * m2;
        if (m < 7) {
#pragma unroll
          for (int kt = 0; kt < 4; ++kt) {
            bf16x8 Af = *(const bf16x8*)&hB[(16 * m + lr) * HROW + kt * 32 + grp * 8];
            a7[m2] = MFMA16(Af, Bf7[kt], a7[m2]);
          }
        }
      }
#pragma unroll
      for (int m2 = 0; m2 < 2; ++m2) {
        int m = w + 4 * m2;
        if (m < 7 && lr < 5) {
#pragma unroll
          for (int rg = 0; rg < 4; ++rg) {
            int row = 16 * m + 4 * grp + rg;
            if (row < 100) dxb[lr * PM + row] = a7[m2][rg] + b7v;
          }
        }
      }
    }
    __syncthreads();

    // ---- residual + softmax(x/T) in fp32; write state to global ----
    if (tid < 100) {
      float invT = 1.f / fmaxf(1.f - (float)step / (float)steps, 0.5f);
      float v[5];
      float mx = -1e30f;
#pragma unroll
      for (int c = 0; c < 5; ++c) {
        v[c] = (xs[c * PM + tid] + dxb[c * PM + tid]) * invT;
        mx = fmaxf(mx, v[c]);
      }
      float sum = 0.f;
#pragma unroll
      for (int c = 0; c < 5; ++c) { v[c] = __expf(v[c] - mx); sum += v[c]; }
      float inv = 1.f / sum;
      size_t sbase = 1024000u + ((size_t)step * NSAMPLES + sample) * 500u;
      size_t fbase = (size_t)sample * 500u;
#pragma unroll
      for (int c = 0; c < 5; ++c) {
        float pv = v[c] * inv;
        xs[c * PM + tid] = pv;
        d_out[sbase + c * 100 + tid] = pv;
        if (step == steps - 1) d_out[fbase + c * 100 + tid] = pv;
      }
    }
    __syncthreads();
  }
}

// ---------------- launch ----------------
extern "C" void kernel_launch(void* const* d_in, const int* in_sizes, int n_in,
                              void* d_out, int out_size, void* d_ws, size_t ws_size,
                              hipStream_t stream) {
  const float* x   = (const float*)d_in[0];
  const float* wp1 = (const float*)d_in[1];
  const float* bp1 = (const float*)d_in[2];
  const float* wp2 = (const float*)d_in[3];
  const float* bp2 = (const float*)d_in[4];
  const float* wp3 = (const float*)d_in[5];
  const float* bp3 = (const float*)d_in[6];
  const float* wu1 = (const float*)d_in[7];
  const float* bu1 = (const float*)d_in[8];
  const float* wu2 = (const float*)d_in[9];
  const float* bu2 = (const float*)d_in[10];
  const float* wu3 = (const float*)d_in[11];
  const float* bu3 = (const float*)d_in[12];
  const float* wu4 = (const float*)d_in[13];
  const float* bu4 = (const float*)d_in[14];
  const int* steps = (const int*)d_in[15];

  // packed bf16 weights in workspace: 223,232 shorts = 446,464 B
  short* W1 = (short*)d_ws;          // [2][8][512]
  short* W2 = W1 + 8192;             // [36][8][512]
  short* W3 = W2 + 147456;           // [4][8][512]
  short* W4 = W3 + 16384;
  short* W5 = W4 + 16384;
  short* W6 = W5 + 16384;
  short* W7 = W6 + 16384;            // [4][1][512]

  prepack_kernel<<<(8192   + 255) / 256, 256, 0, stream>>>(wp1, W1, 1, 8, 45,   128, 8192);
  prepack_kernel<<<(147456 + 255) / 256, 256, 0, stream>>>(wp2, W2, 2, 8, 1152, 128, 147456);
  prepack_kernel<<<(16384  + 255) / 256, 256, 0, stream>>>(wp3, W3, 0, 8, 128,  128, 16384);
  prepack_kernel<<<(16384  + 255) / 256, 256, 0, stream>>>(wu1, W4, 0, 8, 128,  128, 16384);
  prepack_kernel<<<(16384  + 255) / 256, 256, 0, stream>>>(wu2, W5, 0, 8, 128,  128, 16384);
  prepack_kernel<<<(16384  + 255) / 256, 256, 0, stream>>>(wu3, W6, 0, 8, 128,  128, 16384);
  prepack_kernel<<<(2048   + 255) / 256, 256, 0, stream>>>(wu4, W7, 0, 1, 128,  5,   2048);

  nca_kernel<<<NSAMPLES, 256, 0, stream>>>(
      x, bp1, bp2, bp3, bu1, bu2, bu3, bu4,
      W1, W2, W3, W4, W5, W6, W7, steps, (float*)d_out);
}